// Round 1
// baseline (5052.320 us; speedup 1.0000x reference)
//
#include <hip/hip_runtime.h>
#include <hip/hip_bf16.h>

// Problem constants (from reference): B=256, LATENT=64, HID=256, OUT=128, S=512
// gates layout (PyTorch order): [i | f | g | o], each 256 wide -> 4H = 1024.

typedef __bf16 v8bf __attribute__((ext_vector_type(8)));
typedef float  v4f  __attribute__((ext_vector_type(4)));

__device__ __forceinline__ float sigmoidf_(float x) {
    return 1.0f / (1.0f + __expf(-x));   // x very negative -> expf=inf -> 0, safe
}
__device__ __forceinline__ float tanhf_(float x) {
    float ax = fabsf(x);
    float e  = __expf(-2.0f * ax);       // in (0,1], no overflow
    float t  = (1.0f - e) / (1.0f + e);
    return copysignf(t, x);
}

// ---------- K1: h0 = z @ fc_w.T + fc_b  [256,256] ----------
__global__ void h0_kernel(const float* __restrict__ z, const float* __restrict__ fc_w,
                          const float* __restrict__ fc_b, float* __restrict__ h0) {
    __shared__ float zs[64];
    const int b = blockIdx.x, i = threadIdx.x;
    if (i < 64) zs[i] = z[b * 64 + i];
    __syncthreads();
    float acc = fc_b[i];
    #pragma unroll
    for (int k = 0; k < 64; k += 4) {
        float4 w = *(const float4*)(fc_w + i * 64 + k);
        acc += w.x * zs[k] + w.y * zs[k + 1] + w.z * zs[k + 2] + w.w * zs[k + 3];
    }
    h0[b * 256 + i] = acc;
}

// ---------- K2: w_hh fp32 -> bf16 (row-major preserved: [col][k]) ----------
__global__ void cvt_kernel(const float* __restrict__ w, __hip_bfloat16* __restrict__ o) {
    const int i = (blockIdx.x * 256 + threadIdx.x) * 8;   // 128 blocks x 256 thr x 8 = 262144
    const float4 a = *(const float4*)(w + i);
    const float4 b = *(const float4*)(w + i + 4);
    union { __hip_bfloat16 h[8]; uint4 u; } p;
    p.h[0] = __float2bfloat16(a.x); p.h[1] = __float2bfloat16(a.y);
    p.h[2] = __float2bfloat16(a.z); p.h[3] = __float2bfloat16(a.w);
    p.h[4] = __float2bfloat16(b.x); p.h[5] = __float2bfloat16(b.y);
    p.h[6] = __float2bfloat16(b.z); p.h[7] = __float2bfloat16(b.w);
    *(uint4*)(o + i) = p.u;
}

// ---------- K3: x_proj = h0 @ w_ih.T + (b_ih + b_hh)  [256,1024] ----------
__global__ void xproj_kernel(const float* __restrict__ h0, const float* __restrict__ w_ih,
                             const float* __restrict__ b_ih, const float* __restrict__ b_hh,
                             float* __restrict__ xp) {
    __shared__ float hsm[4][256];
    const int tid = threadIdx.x;
    const int r0 = blockIdx.x * 4;                        // 64 blocks x 4 batch rows
    for (int idx = tid; idx < 1024; idx += 256)
        hsm[idx >> 8][idx & 255] = h0[(r0 + (idx >> 8)) * 256 + (idx & 255)];
    __syncthreads();
    float acc[4][4];
    #pragma unroll
    for (int g = 0; g < 4; ++g)
        #pragma unroll
        for (int r = 0; r < 4; ++r) acc[g][r] = 0.f;
    for (int k = 0; k < 256; k += 4) {
        #pragma unroll
        for (int g = 0; g < 4; ++g) {
            const int c = tid + g * 256;
            float4 w = *(const float4*)(w_ih + c * 256 + k);
            #pragma unroll
            for (int r = 0; r < 4; ++r)
                acc[g][r] += w.x * hsm[r][k] + w.y * hsm[r][k + 1]
                           + w.z * hsm[r][k + 2] + w.w * hsm[r][k + 3];
        }
    }
    #pragma unroll
    for (int g = 0; g < 4; ++g) {
        const int c = tid + g * 256;
        const float bias = b_ih[c] + b_hh[c];
        #pragma unroll
        for (int r = 0; r < 4; ++r) xp[(r0 + r) * 1024 + c] = acc[g][r] + bias;
    }
}

// ---------- K4: persistent LSTM + fused output projection ----------
// 16 blocks (16 CUs), 512 threads = 8 waves. Block owns batch rows [16*blk, 16*blk+16).
// Wave w owns gate cols {g*256 + 32w .. +32} for g in 0..3  => each lane's C-frags hold
// all 4 gates for its (m=quad*4+reg, j=32w+16*half+l15) pairs: no cross-lane exchange.
__global__ __launch_bounds__(512, 2) void lstm_persist(
    const float* __restrict__ h0, const float* __restrict__ xp,
    const __hip_bfloat16* __restrict__ wbf,                // w_hh bf16 [1024,256]
    const float* __restrict__ out_w, const float* __restrict__ out_b,
    float* __restrict__ out)                               // [256,512,128]
{
    constexpr int STR = 264;                               // padded LDS row stride (bf16 elems)
    __shared__ __hip_bfloat16 hA[2][16 * STR];             // double-buffered h tile (A-layout)

    const int tid  = threadIdx.x;
    const int wv   = tid >> 6;        // 0..7
    const int lane = tid & 63;
    const int l15  = lane & 15;
    const int quad = lane >> 4;       // 0..3
    const int b_base = blockIdx.x * 16;

    // x_proj -> 32 VGPRs (C-layout), used as MFMA C-initializer each step
    v4f xpr[4][2];
    #pragma unroll
    for (int g = 0; g < 4; ++g)
        #pragma unroll
        for (int h = 0; h < 2; ++h)
            #pragma unroll
            for (int r = 0; r < 4; ++r)
                xpr[g][h][r] = xp[(b_base + quad * 4 + r) * 1024 + g * 256 + wv * 32 + h * 16 + l15];

    // out_w -> register-resident B-frags (wave w owns out cols [16w,16w+16))
    union U8 { __hip_bfloat16 h[8]; v8bf v; };
    v8bf wo[8];
    #pragma unroll
    for (int ks = 0; ks < 8; ++ks) {
        U8 u;
        #pragma unroll
        for (int j = 0; j < 8; ++j)
            u.h[j] = __float2bfloat16(out_w[(wv * 16 + l15) * 256 + ks * 32 + quad * 8 + j]);
        wo[ks] = u.v;
    }
    const float ob = out_b[wv * 16 + l15];

    // stage h_0 (= h0) as bf16 into A-tile buffer 0
    for (int idx = tid; idx < 16 * 256; idx += 512) {
        int m = idx >> 8, k = idx & 255;
        hA[0][m * STR + k] = __float2bfloat16(h0[(b_base + m) * 256 + k]);
    }

    // streamed w_hh B-frag pointers: B[k][n] = w_hh[col=n][k], rows contiguous in k
    const __hip_bfloat16* bp[4][2];
    #pragma unroll
    for (int g = 0; g < 4; ++g)
        #pragma unroll
        for (int h = 0; h < 2; ++h)
            bp[g][h] = wbf + (g * 256 + wv * 32 + h * 16 + l15) * 256 + quad * 8;

    float cst[2][4];
    #pragma unroll
    for (int h = 0; h < 2; ++h)
        #pragma unroll
        for (int r = 0; r < 4; ++r) cst[h][r] = 0.f;

    float* const obase = out + (b_base + quad * 4) * 65536 + wv * 16 + l15;   // 65536 = S*OUT

    __syncthreads();

    for (int t = 0; t < 512; ++t) {
        const __hip_bfloat16* A = hA[t & 1];
        v4f acc[4][2];
        #pragma unroll
        for (int g = 0; g < 4; ++g)
            #pragma unroll
            for (int h = 0; h < 2; ++h) acc[g][h] = xpr[g][h];
        v4f oacc = { ob, ob, ob, ob };

        #pragma unroll
        for (int ks = 0; ks < 8; ++ks) {
            v8bf a = *(const v8bf*)(A + l15 * STR + ks * 32 + quad * 8);
            oacc = __builtin_amdgcn_mfma_f32_16x16x32_bf16(a, wo[ks], oacc, 0, 0, 0);
            #pragma unroll
            for (int g = 0; g < 4; ++g)
                #pragma unroll
                for (int h = 0; h < 2; ++h) {
                    v8bf b = *(const v8bf*)(bp[g][h] + ks * 32);
                    acc[g][h] = __builtin_amdgcn_mfma_f32_16x16x32_bf16(a, b, acc[g][h], 0, 0, 0);
                }
        }

        // out[:, t-1, :] = h_t @ out_w.T + out_b   (h_t is this iteration's A-tile)
        if (t > 0) {
            float* op = obase + (t - 1) * 128;
            #pragma unroll
            for (int r = 0; r < 4; ++r) op[r * 65536] = oacc[r];
        }

        // gate nonlinearities + state update; write h_{t+1} to the other buffer
        __hip_bfloat16* An = hA[(t + 1) & 1];
        #pragma unroll
        for (int h = 0; h < 2; ++h)
            #pragma unroll
            for (int r = 0; r < 4; ++r) {
                float iv = sigmoidf_(acc[0][h][r]);
                float fv = sigmoidf_(acc[1][h][r]);
                float gv = tanhf_  (acc[2][h][r]);
                float ov = sigmoidf_(acc[3][h][r]);
                float c  = fv * cst[h][r] + iv * gv;
                cst[h][r] = c;
                An[(quad * 4 + r) * STR + wv * 32 + h * 16 + l15] =
                    __float2bfloat16(ov * tanhf_(c));
            }
        __syncthreads();
    }

    // epilogue: out[:, 511, :] from h_512 (sits in hA[512 & 1] == hA[0])
    {
        const __hip_bfloat16* A = hA[0];
        v4f oacc = { ob, ob, ob, ob };
        #pragma unroll
        for (int ks = 0; ks < 8; ++ks) {
            v8bf a = *(const v8bf*)(A + l15 * STR + ks * 32 + quad * 8);
            oacc = __builtin_amdgcn_mfma_f32_16x16x32_bf16(a, wo[ks], oacc, 0, 0, 0);
        }
        float* op = obase + 511 * 128;
        #pragma unroll
        for (int r = 0; r < 4; ++r) op[r * 65536] = oacc[r];
    }
}

extern "C" void kernel_launch(void* const* d_in, const int* in_sizes, int n_in,
                              void* d_out, int out_size, void* d_ws, size_t ws_size,
                              hipStream_t stream) {
    (void)in_sizes; (void)n_in; (void)out_size; (void)ws_size;
    const float* z     = (const float*)d_in[0];
    const float* fc_w  = (const float*)d_in[1];
    const float* fc_b  = (const float*)d_in[2];
    const float* w_ih  = (const float*)d_in[3];
    const float* w_hh  = (const float*)d_in[4];
    const float* b_ih  = (const float*)d_in[5];
    const float* b_hh  = (const float*)d_in[6];
    const float* out_w = (const float*)d_in[7];
    const float* out_b = (const float*)d_in[8];

    char* ws = (char*)d_ws;                       // ~1.8 MB used
    float* h0 = (float*)ws;                       // 256*256*4   = 262144 B
    float* xp = (float*)(ws + 262144);            // 256*1024*4  = 1048576 B
    __hip_bfloat16* wbf = (__hip_bfloat16*)(ws + 262144 + 1048576);  // 1024*256*2 = 524288 B
    float* out = (float*)d_out;

    hipLaunchKernelGGL(h0_kernel,    dim3(256), dim3(256), 0, stream, z, fc_w, fc_b, h0);
    hipLaunchKernelGGL(cvt_kernel,   dim3(128), dim3(256), 0, stream, w_hh, wbf);
    hipLaunchKernelGGL(xproj_kernel, dim3(64),  dim3(256), 0, stream, h0, w_ih, b_ih, b_hh, xp);
    hipLaunchKernelGGL(lstm_persist, dim3(16),  dim3(512), 0, stream, h0, xp, wbf, out_w, out_b, out);
}

// Round 3
// 2403.540 us; speedup vs baseline: 2.1020x; 2.1020x over previous
//
#include <hip/hip_runtime.h>
#include <hip/hip_bf16.h>

// B=256, LATENT=64, HID=256, OUT=128, S=512. gates: [i|f|g|o] x 256 -> 4H=1024.
//
// R3 = R2 with the output off-by-one fixed (store proj(h_t) at t-1; epilogue
// stores proj(h_512) at 511) and the pair exchange running at every t so the
// epilogue has the full h_512.
// 32 blocks = 16 pairs. Pair p = blocks {p, p+16} share batch rows [16p,16p+16).
// Block owns j-half (blk>>4) of the gate cols -> w_hh share register-resident
// (128 VGPRs/wave, zero per-step weight traffic). Pair exchanges 4KB h-halves
// per step through L3 (agent atomics + release/acquire flag, double-buffered
// slots, monotonic counter). Out-proj split 64 cols/block on waves 0-3, fused.

typedef __bf16 v8bf __attribute__((ext_vector_type(8)));
typedef float  v4f  __attribute__((ext_vector_type(4)));

__device__ __forceinline__ float sigmoidf_(float x) {
    return 1.0f / (1.0f + __expf(-x));
}
__device__ __forceinline__ float tanhf_(float x) {
    float ax = fabsf(x);
    float e  = __expf(-2.0f * ax);
    float t  = (1.0f - e) / (1.0f + e);
    return copysignf(t, x);
}

// ---------- K0: zero the pair-sync flags ----------
__global__ void zflags_kernel(unsigned int* __restrict__ f) {
    f[threadIdx.x] = 0u;
}

// ---------- K1: h0 = z @ fc_w.T + fc_b ----------
__global__ void h0_kernel(const float* __restrict__ z, const float* __restrict__ fc_w,
                          const float* __restrict__ fc_b, float* __restrict__ h0) {
    __shared__ float zs[64];
    const int b = blockIdx.x, i = threadIdx.x;
    if (i < 64) zs[i] = z[b * 64 + i];
    __syncthreads();
    float acc = fc_b[i];
    #pragma unroll
    for (int k = 0; k < 64; k += 4) {
        float4 w = *(const float4*)(fc_w + i * 64 + k);
        acc += w.x * zs[k] + w.y * zs[k + 1] + w.z * zs[k + 2] + w.w * zs[k + 3];
    }
    h0[b * 256 + i] = acc;
}

// ---------- K2: w_hh fp32 -> bf16 ----------
__global__ void cvt_kernel(const float* __restrict__ w, __hip_bfloat16* __restrict__ o) {
    const int i = (blockIdx.x * 256 + threadIdx.x) * 8;
    const float4 a = *(const float4*)(w + i);
    const float4 b = *(const float4*)(w + i + 4);
    union { __hip_bfloat16 h[8]; uint4 u; } p;
    p.h[0] = __float2bfloat16(a.x); p.h[1] = __float2bfloat16(a.y);
    p.h[2] = __float2bfloat16(a.z); p.h[3] = __float2bfloat16(a.w);
    p.h[4] = __float2bfloat16(b.x); p.h[5] = __float2bfloat16(b.y);
    p.h[6] = __float2bfloat16(b.z); p.h[7] = __float2bfloat16(b.w);
    *(uint4*)(o + i) = p.u;
}

// ---------- K3: x_proj = h0 @ w_ih.T + (b_ih + b_hh) ----------
__global__ void xproj_kernel(const float* __restrict__ h0, const float* __restrict__ w_ih,
                             const float* __restrict__ b_ih, const float* __restrict__ b_hh,
                             float* __restrict__ xp) {
    __shared__ float hsm[4][256];
    const int tid = threadIdx.x;
    const int r0 = blockIdx.x * 4;
    for (int idx = tid; idx < 1024; idx += 256)
        hsm[idx >> 8][idx & 255] = h0[(r0 + (idx >> 8)) * 256 + (idx & 255)];
    __syncthreads();
    float acc[4][4];
    #pragma unroll
    for (int g = 0; g < 4; ++g)
        #pragma unroll
        for (int r = 0; r < 4; ++r) acc[g][r] = 0.f;
    for (int k = 0; k < 256; k += 4) {
        #pragma unroll
        for (int g = 0; g < 4; ++g) {
            const int c = tid + g * 256;
            float4 w = *(const float4*)(w_ih + c * 256 + k);
            #pragma unroll
            for (int r = 0; r < 4; ++r)
                acc[g][r] += w.x * hsm[r][k] + w.y * hsm[r][k + 1]
                           + w.z * hsm[r][k + 2] + w.w * hsm[r][k + 3];
        }
    }
    #pragma unroll
    for (int g = 0; g < 4; ++g) {
        const int c = tid + g * 256;
        const float bias = b_ih[c] + b_hh[c];
        #pragma unroll
        for (int r = 0; r < 4; ++r) xp[(r0 + r) * 1024 + c] = acc[g][r] + bias;
    }
}

// ---------- K4: persistent paired LSTM + fused output projection ----------
__global__ __launch_bounds__(512, 2) void lstm_pair(
    const float* __restrict__ h0, const float* __restrict__ xp,
    const __hip_bfloat16* __restrict__ wbf,          // w_hh bf16 [1024,256]
    const float* __restrict__ out_w, const float* __restrict__ out_b,
    float* __restrict__ out,                          // [256,512,128]
    unsigned long long* __restrict__ stage,           // 32 blk x 2 par x 512 u64
    unsigned int* __restrict__ flags)                 // 32 x (stride 16 u32)
{
    constexpr int STR = 264;
    __shared__ __hip_bfloat16 hA[2][16 * STR];

    const int tid  = threadIdx.x;
    const int wv   = tid >> 6;
    const int lane = tid & 63;
    const int l15  = lane & 15;
    const int quad = lane >> 4;
    const int blk  = blockIdx.x;
    const int half = blk >> 4;                 // j-half this block owns
    const int b_base  = (blk & 15) * 16;       // batch rows
    const int partner = blk ^ 16;
    const int jl    = wv * 16 + l15;           // local j in [0,128)
    const int jcolL = half * 128 + jl;         // col within H

    // w_hh share -> registers: 4 gates x 8 ks fragments (128 VGPRs)
    v8bf wB[4][8];
    #pragma unroll
    for (int g = 0; g < 4; ++g) {
        const __hip_bfloat16* row = wbf + (g * 256 + jcolL) * 256 + quad * 8;
        #pragma unroll
        for (int ks = 0; ks < 8; ++ks)
            wB[g][ks] = *(const v8bf*)(row + ks * 32);
    }

    // x_proj C-init (own cols only)
    v4f xpr[4];
    #pragma unroll
    for (int g = 0; g < 4; ++g)
        #pragma unroll
        for (int r = 0; r < 4; ++r)
            xpr[g][r] = xp[(b_base + quad * 4 + r) * 1024 + g * 256 + jcolL];

    // out-proj frags: block owns out cols [half*64, half*64+64), waves 0-3
    union U8 { __hip_bfloat16 h[8]; v8bf v; };
    v8bf wo[8];
    float ob = 0.f;
    const int ocol = half * 64 + wv * 16 + l15;   // valid for wv<4
    if (wv < 4) {
        #pragma unroll
        for (int ks = 0; ks < 8; ++ks) {
            U8 u;
            #pragma unroll
            for (int j = 0; j < 8; ++j)
                u.h[j] = __float2bfloat16(out_w[ocol * 256 + ks * 32 + quad * 8 + j]);
            wo[ks] = u.v;
        }
        ob = out_b[ocol];
    }

    // stage full h0 tile (both halves) into buffer 0
    for (int idx = tid; idx < 16 * 256; idx += 512) {
        int m = idx >> 8, k = idx & 255;
        hA[0][m * STR + k] = __float2bfloat16(h0[(b_base + m) * 256 + k]);
    }

    float cst[4] = {0.f, 0.f, 0.f, 0.f};

    unsigned long long* ms0 = stage + (blk * 2 + 0) * 512;
    unsigned long long* ms1 = stage + (blk * 2 + 1) * 512;
    const unsigned long long* ps0 = stage + (partner * 2 + 0) * 512;
    const unsigned long long* ps1 = stage + (partner * 2 + 1) * 512;
    unsigned int* mflag = flags + blk * 16;
    unsigned int* pflag = flags + partner * 16;

    float* const obase = out + (b_base + quad * 4) * 65536 + ((wv < 4) ? ocol : 0);

    bool dead = false;
    __syncthreads();

    for (int t = 0; t < 512; ++t) {
        const __hip_bfloat16* A = hA[t & 1];     // holds h_t (full)
        v4f acc[4];
        #pragma unroll
        for (int g = 0; g < 4; ++g) acc[g] = xpr[g];
        v4f oacc = { ob, ob, ob, ob };

        #pragma unroll
        for (int ks = 0; ks < 8; ++ks) {
            v8bf a = *(const v8bf*)(A + l15 * STR + ks * 32 + quad * 8);
            if (wv < 4)
                oacc = __builtin_amdgcn_mfma_f32_16x16x32_bf16(a, wo[ks], oacc, 0, 0, 0);
            #pragma unroll
            for (int g = 0; g < 4; ++g)
                acc[g] = __builtin_amdgcn_mfma_f32_16x16x32_bf16(a, wB[g][ks], acc[g], 0, 0, 0);
        }

        // reference's s-th output is h_{s+1}: proj(h_t) lands at time t-1
        if (t > 0 && wv < 4) {
            #pragma unroll
            for (int r = 0; r < 4; ++r) obase[(t - 1) * 128 + r * 65536] = oacc[r];
        }

        // gate math -> h_{t+1} own half; write LDS next-buf + L3 stage slot
        __hip_bfloat16* An = hA[(t + 1) & 1];
        unsigned short* Ans = (unsigned short*)An;
        union { unsigned short s[4]; unsigned long long u; } pk;
        #pragma unroll
        for (int r = 0; r < 4; ++r) {
            float iv = sigmoidf_(acc[0][r]);
            float fv = sigmoidf_(acc[1][r]);
            float gv = tanhf_  (acc[2][r]);
            float ov = sigmoidf_(acc[3][r]);
            float c  = fv * cst[r] + iv * gv;
            cst[r] = c;
            union { __hip_bfloat16 h; unsigned short u; } cv;
            cv.h = __float2bfloat16(ov * tanhf_(c));
            Ans[(quad * 4 + r) * STR + jcolL] = cv.u;
            pk.s[r] = cv.u;
        }
        unsigned long long* ms = ((t + 1) & 1) ? ms1 : ms0;
        __hip_atomic_store(ms + jl * 4 + quad, pk.u,
                           __ATOMIC_RELAXED, __HIP_MEMORY_SCOPE_AGENT);
        __syncthreads();   // drains vmcnt: all stage stores visible at agent scope

        if (tid == 0)
            __hip_atomic_store(mflag, (unsigned)(t + 1),
                               __ATOMIC_RELEASE, __HIP_MEMORY_SCOPE_AGENT);

        if (!dead) {
            const unsigned want = (unsigned)(t + 1);
            int spins = 0;
            while (__hip_atomic_load(pflag, __ATOMIC_RELAXED,
                                     __HIP_MEMORY_SCOPE_AGENT) < want) {
                __builtin_amdgcn_s_sleep(1);
                if (++spins > (1 << 24)) { dead = true; break; }   // safety valve
            }
            (void)__hip_atomic_load(pflag, __ATOMIC_ACQUIRE, __HIP_MEMORY_SCOPE_AGENT);
            // pull partner's h-half into next A-tile
            const unsigned long long* ps = ((t + 1) & 1) ? ps1 : ps0;
            unsigned long long v = __hip_atomic_load(ps + tid, __ATOMIC_RELAXED,
                                                     __HIP_MEMORY_SCOPE_AGENT);
            const int jp = tid >> 2, q2 = tid & 3;
            #pragma unroll
            for (int r = 0; r < 4; ++r)
                Ans[(q2 * 4 + r) * STR + (half ^ 1) * 128 + jp] =
                    (unsigned short)(v >> (16 * r));
        }
        __syncthreads();
    }

    // epilogue: out[:, 511, :] = proj(h_512); h_512 sits in hA[512 & 1] == hA[0]
    if (wv < 4) {
        const __hip_bfloat16* A = hA[0];
        v4f oacc = { ob, ob, ob, ob };
        #pragma unroll
        for (int ks = 0; ks < 8; ++ks) {
            v8bf a = *(const v8bf*)(A + l15 * STR + ks * 32 + quad * 8);
            oacc = __builtin_amdgcn_mfma_f32_16x16x32_bf16(a, wo[ks], oacc, 0, 0, 0);
        }
        #pragma unroll
        for (int r = 0; r < 4; ++r) obase[511 * 128 + r * 65536] = oacc[r];
    }
}

extern "C" void kernel_launch(void* const* d_in, const int* in_sizes, int n_in,
                              void* d_out, int out_size, void* d_ws, size_t ws_size,
                              hipStream_t stream) {
    (void)in_sizes; (void)n_in; (void)out_size; (void)ws_size;
    const float* z     = (const float*)d_in[0];
    const float* fc_w  = (const float*)d_in[1];
    const float* fc_b  = (const float*)d_in[2];
    const float* w_ih  = (const float*)d_in[3];
    const float* w_hh  = (const float*)d_in[4];
    const float* b_ih  = (const float*)d_in[5];
    const float* b_hh  = (const float*)d_in[6];
    const float* out_w = (const float*)d_in[7];
    const float* out_b = (const float*)d_in[8];

    char* ws = (char*)d_ws;
    float* h0 = (float*)ws;                                          // 256 KB
    float* xp = (float*)(ws + 262144);                               // 1 MB
    __hip_bfloat16* wbf = (__hip_bfloat16*)(ws + 1310720);           // 512 KB
    unsigned int* flags = (unsigned int*)(ws + 1835008);             // 2 KB
    unsigned long long* stage = (unsigned long long*)(ws + 1837056); // 256 KB
    float* out = (float*)d_out;

    hipLaunchKernelGGL(zflags_kernel, dim3(1),   dim3(512), 0, stream, flags);
    hipLaunchKernelGGL(h0_kernel,     dim3(256), dim3(256), 0, stream, z, fc_w, fc_b, h0);
    hipLaunchKernelGGL(cvt_kernel,    dim3(128), dim3(256), 0, stream, w_hh, wbf);
    hipLaunchKernelGGL(xproj_kernel,  dim3(64),  dim3(256), 0, stream, h0, w_ih, b_ih, b_hh, xp);
    hipLaunchKernelGGL(lstm_pair,     dim3(32),  dim3(512), 0, stream,
                       h0, xp, wbf, out_w, out_b, out, stage, flags);
}